// Round 5
// baseline (347.577 us; speedup 1.0000x reference)
//
#include <hip/hip_runtime.h>
#include <math.h>

#define NUM_K 512
#define DIM   64
#define HW    4096
#define IMG   (DIM * HW)
#define OUT_Q 8388608
#define LOSS_OFF OUT_Q
#define IDX_OFF (OUT_Q + 1)
#define TPB   256
#define NBLK  512

typedef float f4 __attribute__((ext_vector_type(4)));

// ||e||^2 per code, d-ascending sequential fp32 (argmin-faithful), into d_ws.
__global__ void vq_prep(const float* __restrict__ emb, float* __restrict__ se) {
  const int k = blockIdx.x * 256 + threadIdx.x;
  const float* e = emb + k * DIM;
  float s = 0.f;
#pragma unroll
  for (int j = 0; j < DIM; ++j) s = fmaf(e[j], e[j], s);
  se[k] = s;
}

__launch_bounds__(TPB, 2)
__global__ void vq_main(const float* __restrict__ in,
                        const float* __restrict__ emb,
                        const float* __restrict__ se,
                        float* __restrict__ out,
                        double* __restrict__ partial) {
  __shared__ double red[TPB / 64];

  const int tid = threadIdx.x;
  const int p   = blockIdx.x * TPB + tid;   // pixel id = n*4096 + h*64 + w
  const int n   = p >> 12;
  const int hw  = p & (HW - 1);
  const float* inp = in + n * IMG + hw;

  // x row in registers (NCHW stride HW; lanes coalesced along w). No pins.
  float xr[DIM];
#pragma unroll
  for (int c = 0; c < DIM; ++c) xr[c] = inp[c * HW];

  // ||x||^2, d-ascending sequential fp32 chain (common-mode across k)
  float sx = 0.f;
#pragma unroll
  for (int c = 0; c < DIM; ++c) sx = fmaf(xr[c], xr[c], sx);

  float best = INFINITY;
  int   bk   = 0;

  // Hot loop: codebook read with WAVE-UNIFORM indices straight from global.
  // No stores in the loop region + __restrict__ => uniformity analysis
  // lowers these to s_load (SMEM pipe, SGPR operands) -> VALU is pure FMA.
  for (int k = 0; k < NUM_K; k += 4) {
    const float* e0 = emb + k * DIM;
    float a0 = 0.f, a1 = 0.f, a2 = 0.f, a3 = 0.f;
#pragma unroll
    for (int j = 0; j < DIM; ++j) {
      const float xj = xr[j];
      a0 = fmaf(xj, e0[j          ], a0);   // 4 independent chains,
      a1 = fmaf(xj, e0[j +     DIM], a1);   // each d-ascending sequential
      a2 = fmaf(xj, e0[j + 2 * DIM], a2);   // (argmin-faithful)
      a3 = fmaf(xj, e0[j + 3 * DIM], a3);
    }
    // d = (||x||^2 + ||e||^2) - 2*dot ; 2*a exact in binary fp.
    const float d0 = (sx + se[k + 0]) - 2.f * a0;
    const float d1 = (sx + se[k + 1]) - 2.f * a1;
    const float d2 = (sx + se[k + 2]) - 2.f * a2;
    const float d3 = (sx + se[k + 3]) - 2.f * a3;
    // strict < with ascending k == np.argmin first-occurrence tie-break
    if (d0 < best) { best = d0; bk = k + 0; }
    if (d1 < best) { best = d1; bk = k + 1; }
    if (d2 < best) { best = d2; bk = k + 2; }
    if (d3 < best) { best = d3; bk = k + 3; }
  }

  // gather quantized row (divergent per-lane row, L2-hot 128 KB codebook)
  const f4* eb4 = (const f4*)(emb + bk * DIM);
  float* outq = out + n * IMG + hw;
  float l = 0.f;
#pragma unroll
  for (int j = 0; j < DIM / 4; ++j) {
    const f4 q = eb4[j];
    outq[(4 * j + 0) * HW] = q.x;   // stores coalesced across lanes (w-contig)
    outq[(4 * j + 1) * HW] = q.y;
    outq[(4 * j + 2) * HW] = q.z;
    outq[(4 * j + 3) * HW] = q.w;
    float dd;
    dd = q.x - xr[4 * j + 0]; l = fmaf(dd, dd, l);
    dd = q.y - xr[4 * j + 1]; l = fmaf(dd, dd, l);
    dd = q.z - xr[4 * j + 2]; l = fmaf(dd, dd, l);
    dd = q.w - xr[4 * j + 3]; l = fmaf(dd, dd, l);
  }
  out[IDX_OFF + p] = (float)bk;   // harness reads whole buffer as fp32

  // block-reduce commitment-loss partial (double) into d_ws
  double ls = (double)l;
#pragma unroll
  for (int o = 32; o; o >>= 1) ls += __shfl_down(ls, o);
  if ((tid & 63) == 0) red[tid >> 6] = ls;
  __syncthreads();
  if (tid == 0) {
    double t = 0.0;
#pragma unroll
    for (int w = 0; w < TPB / 64; ++w) t += red[w];
    partial[blockIdx.x] = t;
  }
}

__global__ void vq_loss(const double* __restrict__ partial, float* __restrict__ out) {
  __shared__ double r2[4];
  const int tid = threadIdx.x;
  double s = partial[tid] + partial[tid + 256];
#pragma unroll
  for (int o = 32; o; o >>= 1) s += __shfl_down(s, o);
  if ((tid & 63) == 0) r2[tid >> 6] = s;
  __syncthreads();
  if (tid == 0) {
    const double t = r2[0] + r2[1] + r2[2] + r2[3];
    out[LOSS_OFF] = (float)(0.25 * t / (double)OUT_Q);
  }
}

extern "C" void kernel_launch(void* const* d_in, const int* in_sizes, int n_in,
                              void* d_out, int out_size, void* d_ws, size_t ws_size,
                              hipStream_t stream) {
  (void)in_sizes; (void)n_in; (void)out_size; (void)ws_size;
  const float* in  = (const float*)d_in[0];
  const float* emb = (const float*)d_in[1];
  float* out = (float*)d_out;
  float*  se      = (float*)d_ws;                       // 512 f32 = 2 KB
  double* partial = (double*)((char*)d_ws + 2048);      // 512 doubles
  vq_prep<<<2, 256, 0, stream>>>(emb, se);
  vq_main<<<NBLK, TPB, 0, stream>>>(in, emb, se, out, partial);
  vq_loss<<<1, 256, 0, stream>>>(partial, out);
}